// Round 1
// baseline (401.201 us; speedup 1.0000x reference)
//
#include <hip/hip_runtime.h>
#include <hip/hip_bf16.h>

#define NF 20000
#define NH 40000
#define NALL 60000
#define NE 640000
#define DD 128
#define AA 64
#define NB 256

// ---------------- helpers ----------------

__device__ __forceinline__ float fast_rcp(float x) {
#if __has_builtin(__builtin_amdgcn_rcpf)
    return __builtin_amdgcn_rcpf(x);
#else
    return 1.f / x;
#endif
}

// tanh(x) = 1 - 2/(exp(2x)+1); exact at +-inf via rcp(inf)=0
__device__ __forceinline__ float tanh_fast(float x) {
    float e = __expf(2.f * x);
    return 1.f - 2.f * fast_rcp(e + 1.f);
}

// ---------------- kernels ----------------

// Detect whether index arrays are int64 (high dwords all zero) or int32.
__global__ void probe_kernel(const unsigned int* __restrict__ fci_raw,
                             int* __restrict__ flag) {
    unsigned int v = fci_raw[threadIdx.x * 2 + 1];
    unsigned long long any = __ballot(v != 0);
    if (threadIdx.x == 0) flag[0] = (any == 0ull) ? 1 : 0;  // 1 => int64
}

__global__ void convert_kernel(const void* __restrict__ cp_raw,
                               const void* __restrict__ fci_raw,
                               int* __restrict__ cp32, int* __restrict__ fci32,
                               const int* __restrict__ flag) {
    int e = blockIdx.x * 256 + threadIdx.x;
    if (e >= NE) return;
    if (flag[0]) {
        cp32[e]  = (int)((const long long*)cp_raw)[e];
        fci32[e] = (int)((const long long*)fci_raw)[e];
    } else {
        cp32[e]  = ((const int*)cp_raw)[e];
        fci32[e] = ((const int*)fci_raw)[e];
    }
}

__global__ void zero_out_kernel(float* __restrict__ out) {
    out[blockIdx.x * 256 + threadIdx.x] = 0.f;
}

// offs[f] = lower_bound(cp32, f) for f in [0, NF]
__global__ void offsets_kernel(const int* __restrict__ cp32, int* __restrict__ offs) {
    int f = blockIdx.x * 256 + threadIdx.x;
    if (f > NF) return;
    int lo = 0, hi = NE;
    while (lo < hi) {
        int mid = (lo + hi) >> 1;
        if (cp32[mid] < f) lo = mid + 1; else hi = mid;
    }
    offs[f] = lo;
}

// P2[i][a] = all_emb[i] @ W2   (blocks [0, NALL/32))
// P1[f][a] = feat_emb[f] @ W1 + bias   (blocks [NALL/32, NALL/32+NF/32))
__global__ __launch_bounds__(256) void proj_kernel(
    const float* __restrict__ feat_emb, const float* __restrict__ hid_emb,
    const float* __restrict__ w_kernel, const float* __restrict__ w_bias,
    float* __restrict__ P1, float* __restrict__ P2)
{
    __shared__ float Wl[128 * 64];      // 32KB: relevant half of w_kernel
    __shared__ float embl[32][128];     // 16KB: 32 embedding rows

    const int blk  = blockIdx.x;
    const bool isP2 = blk < (NALL / 32);
    const int row0 = isP2 ? blk * 32 : (blk - NALL / 32) * 32;
    const int t = threadIdx.x;
    const int kbase = isP2 ? 128 * 64 : 0;   // W2 = rows [128,256), W1 = rows [0,128)

#pragma unroll
    for (int i = 0; i < 32; ++i) {
        int idx = t + i * 256;
        Wl[idx] = w_kernel[kbase + idx];
    }
#pragma unroll
    for (int i = 0; i < 16; ++i) {
        int idx = t + i * 256;
        int r = idx >> 7, c = idx & 127;
        int grow = row0 + r;
        const float* src;
        if (isP2)
            src = (grow < NF) ? (feat_emb + (size_t)grow * DD)
                              : (hid_emb + (size_t)(grow - NF) * DD);
        else
            src = feat_emb + (size_t)grow * DD;
        embl[r][c] = src[c];
    }
    __syncthreads();

    const int a  = t & 63;
    const int rg = t >> 6;   // wave id: rows rg*8 .. rg*8+7
    float acc[8];
#pragma unroll
    for (int j = 0; j < 8; ++j) acc[j] = 0.f;

    for (int k4 = 0; k4 < 32; ++k4) {
        const int k = k4 * 4;
        float w0 = Wl[(k + 0) * 64 + a];
        float w1 = Wl[(k + 1) * 64 + a];
        float w2 = Wl[(k + 2) * 64 + a];
        float w3 = Wl[(k + 3) * 64 + a];
#pragma unroll
        for (int j = 0; j < 8; ++j) {
            const float4 ev = *(const float4*)&embl[rg * 8 + j][k];
            acc[j] = fmaf(ev.x, w0, acc[j]);
            acc[j] = fmaf(ev.y, w1, acc[j]);
            acc[j] = fmaf(ev.z, w2, acc[j]);
            acc[j] = fmaf(ev.w, w3, acc[j]);
        }
    }

    if (isP2) {
#pragma unroll
        for (int j = 0; j < 8; ++j)
            P2[(size_t)(row0 + rg * 8 + j) * AA + a] = acc[j];
    } else {
        float b = w_bias[a];
#pragma unroll
        for (int j = 0; j < 8; ++j)
            P1[(size_t)(row0 + rg * 8 + j) * AA + a] = acc[j] + b;
    }
}

// scores[e] = exp( u . tanh(P1[cp[e]] + P2[fci[e]]) ) * corr[e]
__global__ __launch_bounds__(256) void score_kernel(
    const float* __restrict__ P1, const float* __restrict__ P2,
    const float* __restrict__ u_kernel, const float* __restrict__ corr,
    const int* __restrict__ cp32, const int* __restrict__ fci32,
    float* __restrict__ scores)
{
    int e = blockIdx.x * 256 + threadIdx.x;
    if (e >= NE) return;
    int f = cp32[e], i = fci32[e];
    const float4* p1 = (const float4*)(P1 + (size_t)f * AA);
    const float4* p2 = (const float4*)(P2 + (size_t)i * AA);
    const float4* uk = (const float4*)u_kernel;
    float acc = 0.f;
#pragma unroll
    for (int q = 0; q < 16; ++q) {
        float4 x = p1[q], y = p2[q], u = uk[q];
        acc = fmaf(tanh_fast(x.x + y.x), u.x, acc);
        acc = fmaf(tanh_fast(x.y + y.y), u.y, acc);
        acc = fmaf(tanh_fast(x.z + y.z), u.z, acc);
        acc = fmaf(tanh_fast(x.w + y.w), u.w, acc);
    }
    scores[e] = __expf(acc) * corr[e];
}

// context[f][d] = (sum_e s_e * conn_emb[e][d]) / (sum_e s_e)
__global__ __launch_bounds__(256) void agg_kernel(
    const float* __restrict__ feat_emb, const float* __restrict__ hid_emb,
    const float* __restrict__ scores, const int* __restrict__ offs,
    const int* __restrict__ fci32, float* __restrict__ context)
{
    const int f = blockIdx.x;
    const int t = threadIdx.x;
    const int d = t & 127;
    const int h = t >> 7;                 // 2-way edge parallelism
    const int s0 = offs[f], s1 = offs[f + 1];

    __shared__ float xacc[128];
    __shared__ float xden[1];

    float acc = 0.f, den = 0.f;
    for (int e = s0 + h; e < s1; e += 2) {
        float sc = scores[e];
        int i = fci32[e];
        const float* src = (i < NF) ? (feat_emb + (size_t)i * DD)
                                    : (hid_emb + (size_t)(i - NF) * DD);
        acc = fmaf(sc, src[d], acc);
        den += sc;
    }
    if (h == 1) {
        xacc[d] = acc;
        if (d == 0) xden[0] = den;
    }
    __syncthreads();
    if (h == 0) {
        float at = acc + xacc[d];
        float dt = den + xden[0];
        context[(size_t)f * DD + d] = (s1 > s0) ? at / dt : 0.f;
    }
}

// out[b][d] += values[b][f] * context[f][d]  (split-K, tiled, atomic epilogue)
// grid: x = 4 b-tiles of 64, y = 79 k-chunks of 256
__global__ __launch_bounds__(256) void out_gemm_kernel(
    const float* __restrict__ values, const float* __restrict__ context,
    float* __restrict__ out)
{
    __shared__ float vl[64][64];    // 16KB values tile [b][f]
    __shared__ float cl[64][128];   // 32KB context tile [f][d]

    const int b0 = blockIdx.x * 64;
    const int f0c = blockIdx.y * 256;
    const int t = threadIdx.x;
    const int d = t & 127;
    const int g = t >> 7;           // rows b0 + g*32 + j

    float acc[32];
#pragma unroll
    for (int j = 0; j < 32; ++j) acc[j] = 0.f;

    for (int sub = 0; sub < 4; ++sub) {
        const int f0 = f0c + sub * 64;
        __syncthreads();
#pragma unroll
        for (int i = 0; i < 16; ++i) {
            int idx = t + i * 256;
            int bb = idx >> 6, ff = idx & 63;
            int fg = f0 + ff;
            vl[bb][ff] = (fg < NF) ? values[(size_t)(b0 + bb) * NF + fg] : 0.f;
        }
#pragma unroll
        for (int i = 0; i < 32; ++i) {
            int idx = t + i * 256;
            int ff = idx >> 7, dd = idx & 127;
            int fg = f0 + ff;
            cl[ff][dd] = (fg < NF) ? context[(size_t)fg * DD + dd] : 0.f;
        }
        __syncthreads();

        for (int ff4 = 0; ff4 < 16; ++ff4) {
            float cv0 = cl[ff4 * 4 + 0][d];
            float cv1 = cl[ff4 * 4 + 1][d];
            float cv2 = cl[ff4 * 4 + 2][d];
            float cv3 = cl[ff4 * 4 + 3][d];
#pragma unroll
            for (int j = 0; j < 32; ++j) {
                const float4 v = *(const float4*)&vl[g * 32 + j][ff4 * 4];
                acc[j] = fmaf(v.w, cv3, fmaf(v.z, cv2, fmaf(v.y, cv1, fmaf(v.x, cv0, acc[j]))));
            }
        }
    }
#pragma unroll
    for (int j = 0; j < 32; ++j)
        atomicAdd(&out[(size_t)(b0 + g * 32 + j) * DD + d], acc[j]);
}

// ---------------- launch ----------------

extern "C" void kernel_launch(void* const* d_in, const int* in_sizes, int n_in,
                              void* d_out, int out_size, void* d_ws, size_t ws_size,
                              hipStream_t stream) {
    const float* values   = (const float*)d_in[0];
    const float* feat_emb = (const float*)d_in[1];
    const float* hid_emb  = (const float*)d_in[2];
    const float* w_kernel = (const float*)d_in[3];
    const float* w_bias   = (const float*)d_in[4];
    const float* u_kernel = (const float*)d_in[5];
    const float* corr     = (const float*)d_in[6];
    const void*  cp_raw   = d_in[7];
    const void*  fci_raw  = d_in[8];
    float* out = (float*)d_out;

    char* ws = (char*)d_ws;
    size_t off = 0;
    auto alloc = [&](size_t bytes) {
        size_t cur = off;
        off += (bytes + 511) & ~size_t(511);
        return cur;
    };
    int*   flag    = (int*)  (ws + alloc(4));
    int*   cp32    = (int*)  (ws + alloc(sizeof(int) * NE));
    int*   fci32   = (int*)  (ws + alloc(sizeof(int) * NE));
    int*   offs    = (int*)  (ws + alloc(sizeof(int) * (NF + 1)));
    float* P1      = (float*)(ws + alloc(sizeof(float) * (size_t)NF * AA));
    float* P2      = (float*)(ws + alloc(sizeof(float) * (size_t)NALL * AA));
    float* scores  = (float*)(ws + alloc(sizeof(float) * NE));
    float* context = (float*)(ws + alloc(sizeof(float) * (size_t)NF * DD));

    // 1. dtype probe + index conversion
    probe_kernel<<<1, 64, 0, stream>>>((const unsigned int*)fci_raw, flag);
    convert_kernel<<<(NE + 255) / 256, 256, 0, stream>>>(cp_raw, fci_raw, cp32, fci32, flag);

    // 2. zero the atomic output
    zero_out_kernel<<<(NB * DD) / 256, 256, 0, stream>>>(out);

    // 3. projections P1 / P2
    proj_kernel<<<NALL / 32 + NF / 32, 256, 0, stream>>>(feat_emb, hid_emb, w_kernel,
                                                         w_bias, P1, P2);

    // 4. segment offsets
    offsets_kernel<<<(NF + 1 + 255) / 256, 256, 0, stream>>>(cp32, offs);

    // 5. per-edge attention scores
    score_kernel<<<(NE + 255) / 256, 256, 0, stream>>>(P1, P2, u_kernel, corr,
                                                       cp32, fci32, scores);

    // 6. segment softmax + weighted aggregation -> context
    agg_kernel<<<NF, 256, 0, stream>>>(feat_emb, hid_emb, scores, offs, fci32, context);

    // 7. out = values @ context
    dim3 ggrid(NB / 64, (NF + 255) / 256);
    out_gemm_kernel<<<ggrid, 256, 0, stream>>>(values, context, out);
}

// Round 2
// 331.683 us; speedup vs baseline: 1.2096x; 1.2096x over previous
//
#include <hip/hip_runtime.h>
#include <hip/hip_bf16.h>

#define NF 20000
#define NH 40000
#define NALL 60000
#define NE 640000
#define DD 128
#define AA 64
#define NB 256

// ---------------- helpers ----------------

__device__ __forceinline__ float fast_rcp(float x) {
#if __has_builtin(__builtin_amdgcn_rcpf)
    return __builtin_amdgcn_rcpf(x);
#else
    return 1.f / x;
#endif
}

// tanh(x) = 1 - 2/(exp(2x)+1); exact at +-inf via rcp(inf)=0
__device__ __forceinline__ float tanh_fast(float x) {
    float e = __expf(2.f * x);
    return 1.f - 2.f * fast_rcp(e + 1.f);
}

// ---------------- kernels ----------------

// Detect whether index arrays are int64 (high dwords all zero) or int32.
__global__ void probe_kernel(const unsigned int* __restrict__ fci_raw,
                             int* __restrict__ flag) {
    unsigned int v = fci_raw[threadIdx.x * 2 + 1];
    unsigned long long any = __ballot(v != 0);
    if (threadIdx.x == 0) flag[0] = (any == 0ull) ? 1 : 0;  // 1 => int64
}

__global__ void convert_kernel(const void* __restrict__ cp_raw,
                               const void* __restrict__ fci_raw,
                               int* __restrict__ cp32, int* __restrict__ fci32,
                               const int* __restrict__ flag) {
    int e = blockIdx.x * 256 + threadIdx.x;
    if (e >= NE) return;
    if (flag[0]) {
        cp32[e]  = (int)((const long long*)cp_raw)[e];
        fci32[e] = (int)((const long long*)fci_raw)[e];
    } else {
        cp32[e]  = ((const int*)cp_raw)[e];
        fci32[e] = ((const int*)fci_raw)[e];
    }
}

__global__ void zero_out_kernel(float* __restrict__ out) {
    out[blockIdx.x * 256 + threadIdx.x] = 0.f;
}

// offs[f] = lower_bound(cp32, f) for f in [0, NF]
__global__ void offsets_kernel(const int* __restrict__ cp32, int* __restrict__ offs) {
    int f = blockIdx.x * 256 + threadIdx.x;
    if (f > NF) return;
    int lo = 0, hi = NE;
    while (lo < hi) {
        int mid = (lo + hi) >> 1;
        if (cp32[mid] < f) lo = mid + 1; else hi = mid;
    }
    offs[f] = lo;
}

// P2[i][a] = all_emb[i] @ W2   (blocks [0, NALL/32))
// P1[f][a] = feat_emb[f] @ W1 + bias   (blocks [NALL/32, NALL/32+NF/32))
__global__ __launch_bounds__(256) void proj_kernel(
    const float* __restrict__ feat_emb, const float* __restrict__ hid_emb,
    const float* __restrict__ w_kernel, const float* __restrict__ w_bias,
    float* __restrict__ P1, float* __restrict__ P2)
{
    __shared__ float Wl[128 * 64];      // 32KB: relevant half of w_kernel
    __shared__ float embl[32][128];     // 16KB: 32 embedding rows

    const int blk  = blockIdx.x;
    const bool isP2 = blk < (NALL / 32);
    const int row0 = isP2 ? blk * 32 : (blk - NALL / 32) * 32;
    const int t = threadIdx.x;
    const int kbase = isP2 ? 128 * 64 : 0;   // W2 = rows [128,256), W1 = rows [0,128)

#pragma unroll
    for (int i = 0; i < 32; ++i) {
        int idx = t + i * 256;
        Wl[idx] = w_kernel[kbase + idx];
    }
#pragma unroll
    for (int i = 0; i < 16; ++i) {
        int idx = t + i * 256;
        int r = idx >> 7, c = idx & 127;
        int grow = row0 + r;
        const float* src;
        if (isP2)
            src = (grow < NF) ? (feat_emb + (size_t)grow * DD)
                              : (hid_emb + (size_t)(grow - NF) * DD);
        else
            src = feat_emb + (size_t)grow * DD;
        embl[r][c] = src[c];
    }
    __syncthreads();

    const int a  = t & 63;
    const int rg = t >> 6;   // wave id: rows rg*8 .. rg*8+7
    float acc[8];
#pragma unroll
    for (int j = 0; j < 8; ++j) acc[j] = 0.f;

    for (int k4 = 0; k4 < 32; ++k4) {
        const int k = k4 * 4;
        float w0 = Wl[(k + 0) * 64 + a];
        float w1 = Wl[(k + 1) * 64 + a];
        float w2 = Wl[(k + 2) * 64 + a];
        float w3 = Wl[(k + 3) * 64 + a];
#pragma unroll
        for (int j = 0; j < 8; ++j) {
            const float4 ev = *(const float4*)&embl[rg * 8 + j][k];
            acc[j] = fmaf(ev.x, w0, acc[j]);
            acc[j] = fmaf(ev.y, w1, acc[j]);
            acc[j] = fmaf(ev.z, w2, acc[j]);
            acc[j] = fmaf(ev.w, w3, acc[j]);
        }
    }

    if (isP2) {
#pragma unroll
        for (int j = 0; j < 8; ++j)
            P2[(size_t)(row0 + rg * 8 + j) * AA + a] = acc[j];
    } else {
        float b = w_bias[a];
#pragma unroll
        for (int j = 0; j < 8; ++j)
            P1[(size_t)(row0 + rg * 8 + j) * AA + a] = acc[j] + b;
    }
}

// Fused score + segment-softmax + aggregation.
// One wave per feature; within a wave: half = edge parity, 32 lanes per edge.
//   score_e = exp( u . tanh(P1[f] + P2[fci[e]]) ) * corr[e]
//   context[f][:] = (sum_e score_e * emb[fci[e]][:]) / (sum_e score_e)
__global__ __launch_bounds__(256) void fused_agg_kernel(
    const float* __restrict__ feat_emb, const float* __restrict__ hid_emb,
    const float* __restrict__ P1, const float* __restrict__ P2,
    const float* __restrict__ u_kernel, const float* __restrict__ corr,
    const int* __restrict__ offs, const int* __restrict__ fci32,
    float* __restrict__ context)
{
    const int wave = threadIdx.x >> 6;          // 0..3
    const int lane = threadIdx.x & 63;
    const int h = lane >> 5;                    // edge parity
    const int l = lane & 31;
    const int f = blockIdx.x * 4 + wave;
    if (f >= NF) return;

    const int s0 = offs[f], s1 = offs[f + 1];

    const float2 p1v = ((const float2*)(P1 + (size_t)f * AA))[l];
    const float2 uv  = ((const float2*)u_kernel)[l];

    float4 acc = {0.f, 0.f, 0.f, 0.f};
    float den = 0.f;

    for (int e = s0 + h; e < s1; e += 2) {
        const int i = fci32[e];
        const float cr = corr[e];
        // issue both gathers early
        const float2 p2 = ((const float2*)(P2 + (size_t)i * AA))[l];
        const float* src = (i < NF) ? feat_emb + (size_t)i * DD
                                    : hid_emb + (size_t)(i - NF) * DD;
        const float4 em = ((const float4*)src)[l];

        float part = fmaf(tanh_fast(p1v.x + p2.x), uv.x,
                          tanh_fast(p1v.y + p2.y) * uv.y);
        part += __shfl_xor(part, 1);
        part += __shfl_xor(part, 2);
        part += __shfl_xor(part, 4);
        part += __shfl_xor(part, 8);
        part += __shfl_xor(part, 16);
        const float sc = __expf(part) * cr;

        acc.x = fmaf(sc, em.x, acc.x);
        acc.y = fmaf(sc, em.y, acc.y);
        acc.z = fmaf(sc, em.z, acc.z);
        acc.w = fmaf(sc, em.w, acc.w);
        den += sc;
    }

    // combine the two edge-parity halves
    acc.x += __shfl_xor(acc.x, 32);
    acc.y += __shfl_xor(acc.y, 32);
    acc.z += __shfl_xor(acc.z, 32);
    acc.w += __shfl_xor(acc.w, 32);
    den   += __shfl_xor(den, 32);

    if (h == 0) {
        float4 r = {0.f, 0.f, 0.f, 0.f};
        if (s1 > s0) {
            const float inv = 1.f / den;
            r.x = acc.x * inv; r.y = acc.y * inv;
            r.z = acc.z * inv; r.w = acc.w * inv;
        }
        ((float4*)(context + (size_t)f * DD))[l] = r;
    }
}

// out[b][d] += values[b][f] * context[f][d]  (split-K, tiled, atomic epilogue)
// grid: x = 4 b-tiles of 64, y = 79 k-chunks of 256
__global__ __launch_bounds__(256) void out_gemm_kernel(
    const float* __restrict__ values, const float* __restrict__ context,
    float* __restrict__ out)
{
    __shared__ float vl[64][64];    // 16KB values tile [b][f]
    __shared__ float cl[64][128];   // 32KB context tile [f][d]

    const int b0 = blockIdx.x * 64;
    const int f0c = blockIdx.y * 256;
    const int t = threadIdx.x;
    const int d = t & 127;
    const int g = t >> 7;           // rows b0 + g*32 + j

    float acc[32];
#pragma unroll
    for (int j = 0; j < 32; ++j) acc[j] = 0.f;

    for (int sub = 0; sub < 4; ++sub) {
        const int f0 = f0c + sub * 64;
        __syncthreads();
#pragma unroll
        for (int i = 0; i < 16; ++i) {
            int idx = t + i * 256;
            int bb = idx >> 6, ff = idx & 63;
            int fg = f0 + ff;
            vl[bb][ff] = (fg < NF) ? values[(size_t)(b0 + bb) * NF + fg] : 0.f;
        }
#pragma unroll
        for (int i = 0; i < 32; ++i) {
            int idx = t + i * 256;
            int ff = idx >> 7, dd = idx & 127;
            int fg = f0 + ff;
            cl[ff][dd] = (fg < NF) ? context[(size_t)fg * DD + dd] : 0.f;
        }
        __syncthreads();

        for (int ff4 = 0; ff4 < 16; ++ff4) {
            float cv0 = cl[ff4 * 4 + 0][d];
            float cv1 = cl[ff4 * 4 + 1][d];
            float cv2 = cl[ff4 * 4 + 2][d];
            float cv3 = cl[ff4 * 4 + 3][d];
#pragma unroll
            for (int j = 0; j < 32; ++j) {
                const float4 v = *(const float4*)&vl[g * 32 + j][ff4 * 4];
                acc[j] = fmaf(v.w, cv3, fmaf(v.z, cv2, fmaf(v.y, cv1, fmaf(v.x, cv0, acc[j]))));
            }
        }
    }
#pragma unroll
    for (int j = 0; j < 32; ++j)
        atomicAdd(&out[(size_t)(b0 + g * 32 + j) * DD + d], acc[j]);
}

// ---------------- launch ----------------

extern "C" void kernel_launch(void* const* d_in, const int* in_sizes, int n_in,
                              void* d_out, int out_size, void* d_ws, size_t ws_size,
                              hipStream_t stream) {
    const float* values   = (const float*)d_in[0];
    const float* feat_emb = (const float*)d_in[1];
    const float* hid_emb  = (const float*)d_in[2];
    const float* w_kernel = (const float*)d_in[3];
    const float* w_bias   = (const float*)d_in[4];
    const float* u_kernel = (const float*)d_in[5];
    const float* corr     = (const float*)d_in[6];
    const void*  cp_raw   = d_in[7];
    const void*  fci_raw  = d_in[8];
    float* out = (float*)d_out;

    char* ws = (char*)d_ws;
    size_t off = 0;
    auto alloc = [&](size_t bytes) {
        size_t cur = off;
        off += (bytes + 511) & ~size_t(511);
        return cur;
    };
    int*   flag    = (int*)  (ws + alloc(4));
    int*   cp32    = (int*)  (ws + alloc(sizeof(int) * NE));
    int*   fci32   = (int*)  (ws + alloc(sizeof(int) * NE));
    int*   offs    = (int*)  (ws + alloc(sizeof(int) * (NF + 1)));
    float* P1      = (float*)(ws + alloc(sizeof(float) * (size_t)NF * AA));
    float* P2      = (float*)(ws + alloc(sizeof(float) * (size_t)NALL * AA));
    float* context = (float*)(ws + alloc(sizeof(float) * (size_t)NF * DD));

    // 1. dtype probe + index conversion
    probe_kernel<<<1, 64, 0, stream>>>((const unsigned int*)fci_raw, flag);
    convert_kernel<<<(NE + 255) / 256, 256, 0, stream>>>(cp_raw, fci_raw, cp32, fci32, flag);

    // 2. zero the atomic output
    zero_out_kernel<<<(NB * DD) / 256, 256, 0, stream>>>(out);

    // 3. projections P1 / P2
    proj_kernel<<<NALL / 32 + NF / 32, 256, 0, stream>>>(feat_emb, hid_emb, w_kernel,
                                                         w_bias, P1, P2);

    // 4. segment offsets
    offsets_kernel<<<(NF + 1 + 255) / 256, 256, 0, stream>>>(cp32, offs);

    // 5. fused score + segment softmax + weighted aggregation -> context
    fused_agg_kernel<<<(NF + 3) / 4, 256, 0, stream>>>(feat_emb, hid_emb, P1, P2,
                                                       u_kernel, corr, offs, fci32,
                                                       context);

    // 6. out = values @ context
    dim3 ggrid(NB / 64, (NF + 255) / 256);
    out_gemm_kernel<<<ggrid, 256, 0, stream>>>(values, context, out);
}